// Round 1
// baseline (2077.748 us; speedup 1.0000x reference)
//
#include <hip/hip_runtime.h>
#include <math.h>

// Problem constants (from reference):
//   x: (32, 32, 16, 32, 32) f32, w: (32, 64, 3, 3, 3), bias/gamma/beta: (64,)
//   ConvT3d stride 2, pad 1, out_pad 1 -> conv out (32, 64, 32, 64, 64)
//   + bias + 1.0, LayerNorm over C=64 per (n,d,h,w), AvgPool 2^3 -> (32,64,16,32,32), GELU(tanh)
//
// Gather form of the transposed conv (derived from lhs_dilation=2, pad (1,2)):
//   y[od] taps: od even -> kd=1, id=od/2 ; od odd -> kd=0 id=(od-1)/2, kd=2 id=(od+1)/2
// (same per H and W). Each block: fixed (n, dp, hp, wq); conv tile od in {2dp,2dp+1},
// oh in {2hp, 2hp+1}, ow in [32*wq, 32*wq+32)  -> 128 positions x 64 channels in LDS,
// then LN stats, pool, GELU, store. Input tile (32ci x 2 x 2 x 17) staged in LDS;
// lanes within a wave are the 64 co values -> x reads broadcast, weight reads coalesced.

#define W3_ELEMS (9 * 32 * 64 * 4)  // float4 per (kidx, ci, co), kw in .x/.y/.z

__global__ void reorg_w_kernel(const float* __restrict__ w, float* __restrict__ w3) {
    int t = blockIdx.x * 256 + threadIdx.x;  // over 9*32*64 = 18432
    if (t >= 9 * 32 * 64) return;
    int co = t & 63, ci = (t >> 6) & 31, kidx = t >> 11;  // kidx = kd*3+kh in [0,9)
    const float* src = w + (ci * 64 + co) * 27 + kidx * 3;
    float4 v = make_float4(src[0], src[1], src[2], 0.f);
    ((float4*)w3)[t] = v;
}

__global__ __launch_bounds__(256) void fused_kernel(
    const float* __restrict__ x, const float* __restrict__ w,
    const float* __restrict__ w3, const float* __restrict__ bias,
    const float* __restrict__ gamma, const float* __restrict__ beta,
    float* __restrict__ out, int use_w3)
{
    __shared__ __align__(16) float xs_lds[128 * 20];    // [ci*4 + dd'*2 + hh'][20], cols 0..16 valid
    __shared__ float conv_lds[128 * 65];                // [pos][co], pad 65 -> conflict-free
    float* stats = xs_lds;                              // overlay after phase A: mean[128], rstd[128]

    const int t = threadIdx.x;
    const int b = blockIdx.x;
    const int wq = b & 1;
    const int hp = (b >> 1) & 31;
    const int dp = (b >> 6) & 15;
    const int n  = b >> 10;

    // ---- Phase 0: stage input tile (zero-filled halo) ----
    for (int k = 0; k < 10; ++k) {
        int idx = t + k * 256;              // [0, 2560)
        int col = idx % 20, r = idx / 20;   // r in [0,128)
        int hh = r & 1, ddv = (r >> 1) & 1, ci = r >> 2;
        int iw = wq * 16 + col, ih = hp + hh, id = dp + ddv;
        float v = 0.f;
        if (col < 17 && iw < 32 && ih < 32 && id < 16)
            v = x[(((n * 32 + ci) * 16 + id) * 32 + ih) * 32 + iw];
        xs_lds[idx] = v;
    }
    __syncthreads();

    const int co = t & 63;     // lane within wave = output channel
    const int sg = t >> 6;     // ow-octet: ow_local in [sg*8, sg*8+8)
    const float bco = bias[co] + 1.0f;  // bias + SUM_WEIGHT

    // ---- Phase A: conv into LDS tile ----
    for (int dd = 0; dd < 2; ++dd) {
        for (int hh = 0; hh < 2; ++hh) {
            float acc[8];
#pragma unroll
            for (int j = 0; j < 8; ++j) acc[j] = 0.f;
            const int ndt = dd ? 2 : 1;
            const int nht = hh ? 2 : 1;
            for (int it = 0; it < ndt; ++it) {
                const int kd  = dd ? (it ? 2 : 0) : 1;
                const int idl = dd ? it : 0;
                for (int jt = 0; jt < nht; ++jt) {
                    const int kh  = hh ? (jt ? 2 : 0) : 1;
                    const int ihl = hh ? jt : 0;
                    const int kidx = kd * 3 + kh;
#pragma unroll 4
                    for (int ci = 0; ci < 32; ++ci) {
                        float4 wv;
                        if (use_w3) {
                            wv = ((const float4*)w3)[(kidx * 32 + ci) * 64 + co];
                        } else {
                            const float* wp0 = w + (ci * 64 + co) * 27 + kidx * 3;
                            wv = make_float4(wp0[0], wp0[1], wp0[2], 0.f);
                        }
                        const float* xr = &xs_lds[(ci * 4 + idl * 2 + ihl) * 20 + sg * 4];
                        float4 xa = *(const float4*)xr;  // iw_local sg*4 .. sg*4+3
                        float x4 = xr[4];                // iw_local sg*4+4
                        // even ow (kw=1) and odd ow (kw=0 and kw=2)
                        acc[0] += xa.x * wv.y;
                        acc[1] += xa.x * wv.x + xa.y * wv.z;
                        acc[2] += xa.y * wv.y;
                        acc[3] += xa.y * wv.x + xa.z * wv.z;
                        acc[4] += xa.z * wv.y;
                        acc[5] += xa.z * wv.x + xa.w * wv.z;
                        acc[6] += xa.w * wv.y;
                        acc[7] += xa.w * wv.x + x4 * wv.z;
                    }
                }
            }
            const int posb = (dd * 2 + hh) * 32 + sg * 8;
#pragma unroll
            for (int j = 0; j < 8; ++j)
                conv_lds[(posb + j) * 65 + co] = acc[j] + bco;
        }
    }
    __syncthreads();

    // ---- Phase B: LN stats per spatial position ----
    if (t < 128) {
        float s = 0.f, ss = 0.f;
#pragma unroll 8
        for (int c = 0; c < 64; ++c) {
            float v = conv_lds[t * 65 + c];
            s += v; ss += v * v;
        }
        float mean = s * (1.f / 64.f);
        float var  = ss * (1.f / 64.f) - mean * mean;
        stats[t]       = mean;
        stats[128 + t] = rsqrtf(var + 1e-5f);
    }
    __syncthreads();

    // ---- Phase C: normalize + pool + GELU + store ----
    {
        const int wp  = t & 15;       // pooled w within this block (global wp = wq*16+wp)
        const int cog = t >> 4;       // [0,16): channel group of 4
#pragma unroll
        for (int j = 0; j < 4; ++j) {
            const int c = cog * 4 + j;
            float sum = 0.f;
#pragma unroll
            for (int pd2 = 0; pd2 < 4; ++pd2) {
#pragma unroll
                for (int ww = 0; ww < 2; ++ww) {
                    const int pos = pd2 * 32 + wp * 2 + ww;
                    float v = conv_lds[pos * 65 + c];
                    sum += (v - stats[pos]) * stats[128 + pos];
                }
            }
            float y = sum * 0.125f * gamma[c] + beta[c];
            float u = 0.7978845608028654f * (y + 0.044715f * y * y * y);
            float g = 0.5f * y * (1.f + tanhf(u));
            out[(((n * 64 + c) * 16 + dp) * 32 + hp) * 32 + (wq * 16 + wp)] = g;
        }
    }
}

extern "C" void kernel_launch(void* const* d_in, const int* in_sizes, int n_in,
                              void* d_out, int out_size, void* d_ws, size_t ws_size,
                              hipStream_t stream) {
    const float* x     = (const float*)d_in[0];
    const float* w     = (const float*)d_in[1];
    const float* bias  = (const float*)d_in[2];
    const float* gamma = (const float*)d_in[3];
    const float* beta  = (const float*)d_in[4];
    float* out = (float*)d_out;
    float* w3  = (float*)d_ws;

    const int use_w3 = (ws_size >= W3_ELEMS * sizeof(float)) ? 1 : 0;
    if (use_w3)
        reorg_w_kernel<<<(9 * 32 * 64 + 255) / 256, 256, 0, stream>>>(w, w3);

    // grid: N(32) x Dp(16) x Hp(32) x wq(2) = 32768 blocks
    fused_kernel<<<32768, 256, 0, stream>>>(x, w, w3, bias, gamma, beta, out, use_w3);
}

// Round 2
// 485.528 us; speedup vs baseline: 4.2794x; 4.2794x over previous
//
#include <hip/hip_runtime.h>
#include <math.h>

// ConvT3d(32->64,k3,s2,p1,op1) + bias + 1 + LN(C) + AvgPool2^3 + GELU, fused.
// MFMA formulation: 8 output-parity classes; each (kd,kh,kw) tap belongs to one
// class; pooled[dp,hp,wp] = mean over the 8 per-class LN'd conv values at the
// SAME (dp,hp,wp). Implicit GEMM: M=64 pooled positions, N=64 co, K=32ci per tap.
// Wave = one 16-co tile, all 27 B-frags (bf16 weights, [tap][co][ci]) in VGPRs.
// x tile in LDS as [d][h][w][ci] bf16 -> A-frag = one ds_read_b128.

typedef __attribute__((ext_vector_type(8))) short short8;
typedef __attribute__((ext_vector_type(4))) float f32x4;

__device__ __forceinline__ unsigned short f2bf(float v) {
    unsigned int b = __float_as_uint(v);
    return (unsigned short)((b + 0x7fffu + ((b >> 16) & 1u)) >> 16);
}

// ---- weight prepack: wpack[tap][co][ci] bf16, tap = kd*9+kh*3+kw ----
__global__ void pack_w(const float* __restrict__ w, unsigned short* __restrict__ wp) {
    int t = blockIdx.x * 256 + threadIdx.x;
    if (t >= 27 * 64 * 32) return;
    int ci = t & 31, co = (t >> 5) & 63, tap = t >> 11;
    wp[(tap * 64 + co) * 32 + ci] = f2bf(w[(ci * 64 + co) * 27 + tap]);
}

__global__ __launch_bounds__(256, 2) void mfma_fused(
    const float* __restrict__ x, const unsigned short* __restrict__ wpack,
    const float* __restrict__ bias, const float* __restrict__ gamma,
    const float* __restrict__ beta, float* __restrict__ out)
{
    // class c = pd*4+ph*2+pw; taps grouped per class
    constexpr int COFF[9]   = {0, 1, 3, 5, 9, 11, 15, 19, 27};
    constexpr int TAPIDX[27] = {13, 12,14, 10,16, 9,11,15,17,
                                4,22, 3,5,21,23, 1,7,19,25,
                                0,2,6,8,18,20,24,26};
    // (dd*99 + dh*33 + dw)*32 halfword offsets into xs
    constexpr int XOFF[27]  = {0, 0,32, 0,1056, 0,32,1056,1088,
                               0,3168, 0,32,3168,3200, 0,1056,3168,4224,
                               0,32,1056,1088,3168,3200,4224,4256};

    __shared__ unsigned short xs[6336];      // [dd(2)][hh(3)][ww(33)][ci(32)] bf16
    __shared__ float cbuf[64 * 68];          // [pos][co] pad 68; reused as out_lds [c][64]

    const int t = threadIdx.x;
    const int lane = t & 63;
    const int wv = t >> 6;                   // co tile: co in [wv*16, wv*16+16)
    const int l15 = lane & 15;
    const int quad = lane >> 4;
    const int cobase = wv * 16;

    const int b = blockIdx.x;                // 2048 = 32n x 16dp x 4bq
    const int bq = b & 3;
    const int dp = (b >> 2) & 15;
    const int n = b >> 6;

    // ---- B-fragment preload: 27 x short8 = 108 VGPRs ----
    short8 Breg[27];
#pragma unroll
    for (int u = 0; u < 27; ++u)
        Breg[u] = *(const short8*)(wpack + (TAPIDX[u] * 64 + cobase + l15) * 32 + quad * 8);

    // A-frag base offsets (halfwords) per M-subtile
    int base_hw[4];
#pragma unroll
    for (int s = 0; s < 4; ++s) {
        int m = s * 16 + l15;
        base_hw[s] = ((m >> 5) * 33 + (m & 31)) * 32 + quad * 8;
    }

    const float bco = bias[cobase + l15] + 1.0f;   // + SUM_WEIGHT
    const int p = t >> 2, qq = t & 3;              // LN: 4 threads per position
    f32x4 gm[4], bt[4];
#pragma unroll
    for (int jj = 0; jj < 4; ++jj) {
        gm[jj] = *(const f32x4*)(gamma + qq * 16 + jj * 4);
        bt[jj] = *(const f32x4*)(beta + qq * 16 + jj * 4);
    }

    for (int it = 0; it < 4; ++it) {
        const int hp0 = (bq * 4 + it) * 2;
        __syncthreads();   // xs / cbuf safe to overwrite

        // ---- stage x tile -> bf16 LDS, zero halo ----
        for (int i = t; i < 6336; i += 256) {
            int ww = i % 33, r = i / 33;           // r = ci*6 + dd*3 + hh
            int hh = r % 3, rd = r / 3;
            int dd = rd & 1, ci = rd >> 1;
            int id = dp + dd, ih = hp0 + hh;
            float v = 0.f;
            if (ww < 32 && ih < 32 && id < 16)
                v = x[((n * 32 + ci) * 16 + id) * 1024 + ih * 32 + ww];
            xs[((dd * 3 + hh) * 33 + ww) * 32 + ci] = f2bf(v);
        }
        __syncthreads();

        float pool[16];
#pragma unroll
        for (int j = 0; j < 16; ++j) pool[j] = 0.f;

#pragma unroll
        for (int c = 0; c < 8; ++c) {
            f32x4 acc[4];
#pragma unroll
            for (int s = 0; s < 4; ++s) acc[s] = (f32x4)0.f;

#pragma unroll
            for (int u = COFF[c]; u < COFF[c + 1]; ++u) {
#pragma unroll
                for (int s = 0; s < 4; ++s) {
                    short8 a = *(const short8*)(xs + base_hw[s] + XOFF[u]);
                    acc[s] = __builtin_amdgcn_mfma_f32_16x16x32_bf16(a, Breg[u], acc[s], 0, 0, 0);
                }
            }
            // D -> cbuf[pos][co]  (row = quad*4+reg, col = l15)
#pragma unroll
            for (int s = 0; s < 4; ++s)
#pragma unroll
                for (int r = 0; r < 4; ++r)
                    cbuf[(s * 16 + quad * 4 + r) * 68 + cobase + l15] = acc[s][r] + bco;
            __syncthreads();

            // LN over 64 channels at position p (4 threads x 16 ch)
            f32x4 vv[4];
#pragma unroll
            for (int jj = 0; jj < 4; ++jj)
                vv[jj] = *(const f32x4*)&cbuf[p * 68 + qq * 16 + jj * 4];
            float s1 = 0.f, s2 = 0.f;
#pragma unroll
            for (int jj = 0; jj < 4; ++jj)
#pragma unroll
                for (int k = 0; k < 4; ++k) { float v = vv[jj][k]; s1 += v; s2 += v * v; }
            s1 += __shfl_xor(s1, 1); s2 += __shfl_xor(s2, 1);
            s1 += __shfl_xor(s1, 2); s2 += __shfl_xor(s2, 2);
            float mean = s1 * (1.f / 64.f);
            float var = s2 * (1.f / 64.f) - mean * mean;
            float rstd = rsqrtf(var + 1e-5f);
#pragma unroll
            for (int jj = 0; jj < 4; ++jj)
#pragma unroll
                for (int k = 0; k < 4; ++k)
                    pool[jj * 4 + k] += (vv[jj][k] - mean) * rstd;
            __syncthreads();   // before next class overwrites cbuf
        }

        // ---- finalize: /8, gamma/beta, GELU; transpose via cbuf for coalesced store ----
#pragma unroll
        for (int jj = 0; jj < 4; ++jj)
#pragma unroll
            for (int k = 0; k < 4; ++k) {
                float y = pool[jj * 4 + k] * 0.125f * gm[jj][k] + bt[jj][k];
                float u = 0.7978845608028654f * (y + 0.044715f * y * y * y);
                float g = y / (1.f + __expf(-2.f * u));   // 0.5y(1+tanh(u))
                cbuf[(qq * 16 + jj * 4 + k) * 64 + p] = g;
            }
        __syncthreads();
#pragma unroll
        for (int k = 0; k < 16; ++k) {
            int idx = k * 256 + t;
            int c = idx >> 6, pp = idx & 63;
            out[((n * 64 + c) * 16 + dp) * 1024 + hp0 * 32 + pp] = cbuf[c * 64 + pp];
        }
    }
}

// ---- fallback (round-0 fp32 path, direct weight reads) if ws too small ----
__global__ __launch_bounds__(256) void fused_fallback(
    const float* __restrict__ x, const float* __restrict__ w,
    const float* __restrict__ bias, const float* __restrict__ gamma,
    const float* __restrict__ beta, float* __restrict__ out)
{
    __shared__ __align__(16) float xs_lds[128 * 20];
    __shared__ float conv_lds[128 * 65];
    float* stats = xs_lds;

    const int t = threadIdx.x;
    const int b = blockIdx.x;
    const int wq = b & 1;
    const int hp = (b >> 1) & 31;
    const int dp = (b >> 6) & 15;
    const int n = b >> 10;

    for (int k = 0; k < 10; ++k) {
        int idx = t + k * 256;
        int col = idx % 20, r = idx / 20;
        int hh = r & 1, ddv = (r >> 1) & 1, ci = r >> 2;
        int iw = wq * 16 + col, ih = hp + hh, id = dp + ddv;
        float v = 0.f;
        if (col < 17 && iw < 32 && ih < 32 && id < 16)
            v = x[(((n * 32 + ci) * 16 + id) * 32 + ih) * 32 + iw];
        xs_lds[idx] = v;
    }
    __syncthreads();

    const int co = t & 63;
    const int sg = t >> 6;
    const float bco = bias[co] + 1.0f;

    for (int dd = 0; dd < 2; ++dd)
        for (int hh = 0; hh < 2; ++hh) {
            float acc[8];
#pragma unroll
            for (int j = 0; j < 8; ++j) acc[j] = 0.f;
            const int ndt = dd ? 2 : 1, nht = hh ? 2 : 1;
            for (int itp = 0; itp < ndt; ++itp) {
                const int kd = dd ? (itp ? 2 : 0) : 1;
                const int idl = dd ? itp : 0;
                for (int jt = 0; jt < nht; ++jt) {
                    const int kh = hh ? (jt ? 2 : 0) : 1;
                    const int ihl = hh ? jt : 0;
                    const int kidx = kd * 3 + kh;
#pragma unroll 4
                    for (int ci = 0; ci < 32; ++ci) {
                        const float* wp0 = w + (ci * 64 + co) * 27 + kidx * 3;
                        float w0 = wp0[0], w1 = wp0[1], w2 = wp0[2];
                        const float* xr = &xs_lds[(ci * 4 + idl * 2 + ihl) * 20 + sg * 4];
                        float4 xa = *(const float4*)xr;
                        float x4 = xr[4];
                        acc[0] += xa.x * w1;
                        acc[1] += xa.x * w0 + xa.y * w2;
                        acc[2] += xa.y * w1;
                        acc[3] += xa.y * w0 + xa.z * w2;
                        acc[4] += xa.z * w1;
                        acc[5] += xa.z * w0 + xa.w * w2;
                        acc[6] += xa.w * w1;
                        acc[7] += xa.w * w0 + x4 * w2;
                    }
                }
            }
            const int posb = (dd * 2 + hh) * 32 + sg * 8;
#pragma unroll
            for (int j = 0; j < 8; ++j)
                conv_lds[(posb + j) * 65 + co] = acc[j] + bco;
        }
    __syncthreads();

    if (t < 128) {
        float s = 0.f, ss = 0.f;
#pragma unroll 8
        for (int c = 0; c < 64; ++c) { float v = conv_lds[t * 65 + c]; s += v; ss += v * v; }
        float mean = s * (1.f / 64.f);
        float var = ss * (1.f / 64.f) - mean * mean;
        stats[t] = mean;
        stats[128 + t] = rsqrtf(var + 1e-5f);
    }
    __syncthreads();

    {
        const int wp = t & 15, cog = t >> 4;
#pragma unroll
        for (int j = 0; j < 4; ++j) {
            const int c = cog * 4 + j;
            float sum = 0.f;
#pragma unroll
            for (int pd2 = 0; pd2 < 4; ++pd2)
#pragma unroll
                for (int ww = 0; ww < 2; ++ww) {
                    const int pos = pd2 * 32 + wp * 2 + ww;
                    sum += (conv_lds[pos * 65 + c] - stats[pos]) * stats[128 + pos];
                }
            float y = sum * 0.125f * gamma[c] + beta[c];
            float u = 0.7978845608028654f * (y + 0.044715f * y * y * y);
            float g = 0.5f * y * (1.f + tanhf(u));
            out[(((n * 64 + c) * 16 + dp) * 32 + hp) * 32 + (wq * 16 + wp)] = g;
        }
    }
}

extern "C" void kernel_launch(void* const* d_in, const int* in_sizes, int n_in,
                              void* d_out, int out_size, void* d_ws, size_t ws_size,
                              hipStream_t stream) {
    const float* x = (const float*)d_in[0];
    const float* w = (const float*)d_in[1];
    const float* bias = (const float*)d_in[2];
    const float* gamma = (const float*)d_in[3];
    const float* beta = (const float*)d_in[4];
    float* out = (float*)d_out;

    const size_t need = (size_t)(27 * 64 * 32) * sizeof(unsigned short);
    if (ws_size >= need) {
        unsigned short* wpack = (unsigned short*)d_ws;
        pack_w<<<(27 * 64 * 32 + 255) / 256, 256, 0, stream>>>(w, wpack);
        mfma_fused<<<2048, 256, 0, stream>>>(x, wpack, bias, gamma, beta, out);
    } else {
        fused_fallback<<<32768, 256, 0, stream>>>(x, w, bias, gamma, beta, out);
    }
}